// Round 1
// baseline (1290.116 us; speedup 1.0000x reference)
//
#include <hip/hip_runtime.h>
#include <hip/hip_bf16.h>

// Problem constants (from setup_inputs)
#define N_EMB   6272
#define M_BANK  32768
#define D_DIM   128
#define BATCH   8
#define P_PATCH 784      // 6272 / 8
#define GRID_WH 28
#define OUT_WH  224
#define KNN     9
#define KSIZE   33
#define KRAD    16

#define TILE 128
#define KB   32
#define LDA  132   // 128 + 4 pad, keeps 16B alignment

typedef unsigned long long ull;

// ---------------- workspace layout (bytes) ----------------
// minpack  : u64[N_EMB]            @ 0        (50176)
// x2       : f32[N_EMB]            @ 50176    (25088)
// y2       : f32[M_BANK]           @ 75264    (131072)
// pscore   : f32[N_EMB]            @ 206336   (25088)
// loc      : i32[N_EMB]            @ 231424   (25088)
// bscore   : f32[8]                @ 256512
// bmaxp    : i32[8]                @ 256544
// bnn      : i32[8]                @ 256576
// dnn      : f32[8*M_BANK]         @ 256608.. round up to 256640
// amap     : f32[8*224*224]        @ 1305216
// tmp      : f32[8*224*224]        @ 2910848
#define WS_MINPACK 0
#define WS_X2      50176
#define WS_Y2      75264
#define WS_PSCORE  206336
#define WS_LOC     231424
#define WS_BSCORE  256512
#define WS_BMAXP   256544
#define WS_BNN     256576
#define WS_DNN     256640
#define WS_AMAP    1305216
#define WS_TMP     2910848

__device__ __forceinline__ ull umin64(ull a, ull b) { return a < b ? a : b; }
__device__ __forceinline__ ull umax64(ull a, ull b) { return a > b ? a : b; }

// ---------------------------------------------------------------------------
// Kernel 0: row sum-of-squares for embedding (x2) and memory bank (y2).
// One wave per row; lane handles 2 floats; shuffle reduce.
// ---------------------------------------------------------------------------
__global__ __launch_bounds__(256) void sumsq_kernel(
    const float* __restrict__ emb, const float* __restrict__ bank,
    float* __restrict__ x2, float* __restrict__ y2)
{
    int w    = blockIdx.x * 4 + (threadIdx.x >> 6);
    int lane = threadIdx.x & 63;
    const float* src;
    float* dst;
    if (w < M_BANK) { src = bank + (size_t)w * D_DIM; dst = y2 + w; }
    else            { int e = w - M_BANK; if (e >= N_EMB) return;
                      src = emb + (size_t)e * D_DIM; dst = x2 + e; }
    float2 v = *(const float2*)&src[2 * lane];
    float s = fmaf(v.x, v.x, v.y * v.y);
    #pragma unroll
    for (int off = 32; off > 0; off >>= 1) s += __shfl_down(s, off, 64);
    if (lane == 0) *dst = s;
}

// ---------------------------------------------------------------------------
// Kernel 1: fused distance + min/argmin.
// Block tile: 128 e-rows x 128 m-cols, K=128 in 4 chunks of 32.
// 256 threads as 16x16, each owns an 8x8 micro-tile.
// Running min kept as packed (f32bits(d2)<<32 | m_idx); block-reduced, then
// atomicMin(u64) into global minpack.
// ---------------------------------------------------------------------------
__global__ __launch_bounds__(256) void min_dist_kernel(
    const float* __restrict__ emb, const float* __restrict__ bank,
    const float* __restrict__ x2, const float* __restrict__ y2,
    ull* __restrict__ minpack)
{
    __shared__ __align__(16) float smem[2 * KB * LDA];  // 33792 B
    float (*As)[LDA] = (float (*)[LDA])smem;
    float (*Bs)[LDA] = (float (*)[LDA])(smem + KB * LDA);

    const int tid = threadIdx.x;
    const int tx = tid & 15, ty = tid >> 4;
    const int et = blockIdx.y;           // 0..48
    const int mc = blockIdx.x;           // 0..31 (chunk of 1024 m-rows)
    const int erow0 = et * TILE + ty * 8;

    ull runmin[8];
    float x2r[8];
    #pragma unroll
    for (int i = 0; i < 8; ++i) {
        runmin[i] = ~0ull;
        x2r[i] = x2[erow0 + i];
    }

    for (int mt = 0; mt < 8; ++mt) {
        const int m0 = mc * 1024 + mt * TILE;
        float acc[8][8];
        #pragma unroll
        for (int i = 0; i < 8; ++i)
            #pragma unroll
            for (int j = 0; j < 8; ++j) acc[i][j] = 0.0f;

        for (int ks = 0; ks < D_DIM; ks += KB) {
            // stage A (128 x 32) and B (128 x 32) transposed into LDS
            #pragma unroll
            for (int q = 0; q < 4; ++q) {
                int f   = tid + q * 256;       // 0..1023
                int row = f >> 3;              // 0..127
                int kq  = (f & 7) * 4;         // 0..28
                float4 va = *(const float4*)&emb[(size_t)(et * TILE + row) * D_DIM + ks + kq];
                As[kq + 0][row] = va.x; As[kq + 1][row] = va.y;
                As[kq + 2][row] = va.z; As[kq + 3][row] = va.w;
                float4 vb = *(const float4*)&bank[(size_t)(m0 + row) * D_DIM + ks + kq];
                Bs[kq + 0][row] = vb.x; Bs[kq + 1][row] = vb.y;
                Bs[kq + 2][row] = vb.z; Bs[kq + 3][row] = vb.w;
            }
            __syncthreads();
            for (int k = 0; k < KB; ++k) {
                float a[8], b[8];
                *(float4*)&a[0] = *(const float4*)&As[k][ty * 8];
                *(float4*)&a[4] = *(const float4*)&As[k][ty * 8 + 4];
                *(float4*)&b[0] = *(const float4*)&Bs[k][tx * 8];
                *(float4*)&b[4] = *(const float4*)&Bs[k][tx * 8 + 4];
                #pragma unroll
                for (int i = 0; i < 8; ++i)
                    #pragma unroll
                    for (int j = 0; j < 8; ++j)
                        acc[i][j] = fmaf(a[i], b[j], acc[i][j]);
            }
            __syncthreads();
        }

        // epilogue: d2 = x2 + y2 - 2*dot, clamp, pack, running min
        #pragma unroll
        for (int j = 0; j < 8; ++j) {
            int m = m0 + tx * 8 + j;
            float y2v = y2[m];
            #pragma unroll
            for (int i = 0; i < 8; ++i) {
                float d2 = fmaf(-2.0f, acc[i][j], x2r[i] + y2v);
                d2 = fmaxf(d2, 0.0f);
                ull p = ((ull)__float_as_uint(d2) << 32) | (unsigned)m;
                runmin[i] = umin64(runmin[i], p);
            }
        }
    }

    // block reduction across the 16 column-groups per e-row
    __syncthreads();
    ull* Red = (ull*)smem;   // 128*16*8 = 16384 B, fits
    #pragma unroll
    for (int i = 0; i < 8; ++i) Red[(ty * 8 + i) * 16 + tx] = runmin[i];
    __syncthreads();
    if (tid < 128) {
        ull v = Red[tid * 16];
        #pragma unroll
        for (int t = 1; t < 16; ++t) v = umin64(v, Red[tid * 16 + t]);
        atomicMin(&minpack[et * TILE + tid], v);
    }
}

// ---------------------------------------------------------------------------
// Kernel 2: unpack minpack -> patch_scores (sqrt of min d2) and locations
// ---------------------------------------------------------------------------
__global__ __launch_bounds__(256) void finalize_nn_kernel(
    const ull* __restrict__ minpack, float* __restrict__ pscore, int* __restrict__ loc)
{
    int i = blockIdx.x * 256 + threadIdx.x;
    if (i < N_EMB) {
        ull p = minpack[i];
        pscore[i] = sqrtf(__uint_as_float((unsigned)(p >> 32)));
        loc[i]    = (int)(p & 0xFFFFFFFFu);
    }
}

// ---------------------------------------------------------------------------
// Kernel 3: per-batch argmax of patch_scores (first-index tie-break)
// ---------------------------------------------------------------------------
__global__ __launch_bounds__(256) void batch_argmax_kernel(
    const float* __restrict__ pscore, const int* __restrict__ loc,
    float* __restrict__ bscore, int* __restrict__ bmaxp, int* __restrict__ bnn)
{
    __shared__ ull red[256];
    int b = blockIdx.x, tid = threadIdx.x;
    ull local = 0;
    for (int p = tid; p < P_PATCH; p += 256) {
        float s = pscore[b * P_PATCH + p];
        ull pk = ((ull)__float_as_uint(s) << 32) | (unsigned)(p ^ 0xFFFFFFFFu);
        local = umax64(local, pk);
    }
    red[tid] = local;
    __syncthreads();
    for (int s = 128; s > 0; s >>= 1) {
        if (tid < s) red[tid] = umax64(red[tid], red[tid + s]);
        __syncthreads();
    }
    if (tid == 0) {
        ull r = red[0];
        int p = (int)(((unsigned)(r & 0xFFFFFFFFu)) ^ 0xFFFFFFFFu);
        bscore[b] = __uint_as_float((unsigned)(r >> 32));
        bmaxp[b]  = p;
        bnn[b]    = loc[b * P_PATCH + p];
    }
}

// ---------------------------------------------------------------------------
// Kernel 4: d_nn = dist(nn_sample[b], memory_bank)  -> (8, M)
// One wave per m-row, all 8 batches per wave; nn rows staged in LDS.
// ---------------------------------------------------------------------------
__global__ __launch_bounds__(256) void dnn_kernel(
    const float* __restrict__ bank, const float* __restrict__ y2,
    const int* __restrict__ bnn, float* __restrict__ dnn)
{
    __shared__ float nn[BATCH][D_DIM];
    __shared__ float nny2[BATCH];
    int tid = threadIdx.x;
    for (int i = tid; i < BATCH * D_DIM; i += 256) {
        int b = i >> 7, d = i & 127;
        nn[b][d] = bank[(size_t)bnn[b] * D_DIM + d];
    }
    if (tid < BATCH) nny2[tid] = y2[bnn[tid]];
    __syncthreads();

    int w = tid >> 6, lane = tid & 63;
    int m = blockIdx.x * 4 + w;
    float2 v = *(const float2*)&bank[(size_t)m * D_DIM + 2 * lane];
    float part[BATCH];
    #pragma unroll
    for (int b = 0; b < BATCH; ++b)
        part[b] = fmaf(v.x, nn[b][2 * lane], v.y * nn[b][2 * lane + 1]);
    #pragma unroll
    for (int b = 0; b < BATCH; ++b) {
        float s = part[b];
        #pragma unroll
        for (int off = 32; off > 0; off >>= 1) s += __shfl_down(s, off, 64);
        if (lane == 0) {
            float d2 = nny2[b] + y2[m] - 2.0f * s;
            dnn[b * M_BANK + m] = sqrtf(fmaxf(d2, 0.0f));
        }
    }
}

// ---------------------------------------------------------------------------
// Kernel 5: per-batch top-9 smallest d_nn (lowest-index tie-break), then
// re-score: dists(max_feat, support) -> softmax -> pred_score.
// ---------------------------------------------------------------------------
__global__ __launch_bounds__(256) void topk_score_kernel(
    const float* __restrict__ emb, const float* __restrict__ bank,
    const float* __restrict__ x2, const float* __restrict__ y2,
    const float* __restrict__ dnn, const float* __restrict__ bscore,
    const int* __restrict__ bmaxp, float* __restrict__ out)
{
    __shared__ ull red[256];
    __shared__ int chosen[KNN];
    __shared__ float dists[KNN];
    int b = blockIdx.x, tid = threadIdx.x;

    for (int k = 0; k < KNN; ++k) {
        ull local = ~0ull;
        for (int i = tid; i < M_BANK; i += 256) {
            bool skip = false;
            for (int j = 0; j < k; ++j) skip |= (chosen[j] == i);
            if (!skip) {
                float d = dnn[b * M_BANK + i];
                ull pk = ((ull)__float_as_uint(d) << 32) | (unsigned)i;
                local = umin64(local, pk);
            }
        }
        red[tid] = local;
        __syncthreads();
        for (int s = 128; s > 0; s >>= 1) {
            if (tid < s) red[tid] = umin64(red[tid], red[tid + s]);
            __syncthreads();
        }
        if (tid == 0) chosen[k] = (int)(red[0] & 0xFFFFFFFFu);
        __syncthreads();
    }

    int e = b * P_PATCH + bmaxp[b];
    if (tid < KNN) {
        const float* mf = emb + (size_t)e * D_DIM;
        const float* ms = bank + (size_t)chosen[tid] * D_DIM;
        float dot = 0.0f;
        for (int d = 0; d < D_DIM; ++d) dot = fmaf(mf[d], ms[d], dot);
        float d2 = x2[e] - 2.0f * dot + y2[chosen[tid]];
        dists[tid] = sqrtf(fmaxf(d2, 0.0f));
    }
    __syncthreads();
    if (tid == 0) {
        float mx = dists[0];
        for (int k = 1; k < KNN; ++k) mx = fmaxf(mx, dists[k]);
        float s = 0.0f;
        for (int k = 0; k < KNN; ++k) s += expf(dists[k] - mx);
        float w = 1.0f - expf(dists[0] - mx) / s;
        out[b] = w * bscore[b];
    }
}

// ---------------------------------------------------------------------------
// Kernel 6: bilinear resize 28x28 -> 224x224 (align_corners=False semantics)
// ---------------------------------------------------------------------------
__global__ __launch_bounds__(256) void resize_kernel(
    const float* __restrict__ pscore, float* __restrict__ amap)
{
    int o = blockIdx.x * 256 + threadIdx.x;          // 0..401407
    int b = o / (OUT_WH * OUT_WH);
    int r = (o / OUT_WH) % OUT_WH;
    int c = o % OUT_WH;
    float cy = (2 * r - 7) * 0.0625f;
    float cx = (2 * c - 7) * 0.0625f;
    int iy = (int)floorf(cy); float fy = cy - iy;
    int ix = (int)floorf(cx); float fx = cx - ix;
    int y0 = min(max(iy, 0), GRID_WH - 1), y1 = min(max(iy + 1, 0), GRID_WH - 1);
    int x0 = min(max(ix, 0), GRID_WH - 1), x1 = min(max(ix + 1, 0), GRID_WH - 1);
    const float* ps = pscore + b * P_PATCH;
    float v00 = ps[y0 * GRID_WH + x0], v01 = ps[y0 * GRID_WH + x1];
    float v10 = ps[y1 * GRID_WH + x0], v11 = ps[y1 * GRID_WH + x1];
    float top = (1.0f - fx) * v00 + fx * v01;
    float bot = (1.0f - fx) * v10 + fx * v11;
    amap[o] = (1.0f - fy) * top + fy * bot;
}

// ---------------------------------------------------------------------------
// Kernels 7/8: separable 33-tap Gaussian blur, reflect padding.
// Pass V along H (dim 2) first, then pass H along W (dim 3) — same order as ref.
// ---------------------------------------------------------------------------
__device__ __forceinline__ int refl224(int i) {
    if (i < 0) i = -i;
    if (i >= OUT_WH) i = 2 * (OUT_WH - 1) - i;
    return i;
}

__device__ __forceinline__ void make_gauss(float* g, int tid) {
    if (tid < KSIZE) {
        float x = (tid - KRAD) * 0.25f;      // /SIGMA = /4
        g[tid] = __expf(-0.5f * x * x);
    }
    __syncthreads();
    if (tid == 0) {
        float s = 0.0f;
        for (int i = 0; i < KSIZE; ++i) s += g[i];
        float inv = 1.0f / s;
        for (int i = 0; i < KSIZE; ++i) g[i] *= inv;
    }
    __syncthreads();
}

__global__ __launch_bounds__(256) void blur_v_kernel(
    const float* __restrict__ in, float* __restrict__ outp)
{
    __shared__ float g[KSIZE];
    int tid = threadIdx.x;
    make_gauss(g, tid);
    int o = blockIdx.x * 256 + tid;
    int b = o / (OUT_WH * OUT_WH);
    int y = (o / OUT_WH) % OUT_WH;
    int x = o % OUT_WH;
    const float* src = in + (size_t)b * OUT_WH * OUT_WH;
    float s = 0.0f;
    #pragma unroll
    for (int t = 0; t < KSIZE; ++t)
        s = fmaf(g[t], src[refl224(y - KRAD + t) * OUT_WH + x], s);
    outp[o] = s;
}

__global__ __launch_bounds__(256) void blur_h_kernel(
    const float* __restrict__ in, float* __restrict__ outp)
{
    __shared__ float g[KSIZE];
    int tid = threadIdx.x;
    make_gauss(g, tid);
    int o = blockIdx.x * 256 + tid;
    int b = o / (OUT_WH * OUT_WH);
    int y = (o / OUT_WH) % OUT_WH;
    int x = o % OUT_WH;
    const float* src = in + (size_t)b * OUT_WH * OUT_WH + (size_t)y * OUT_WH;
    float s = 0.0f;
    #pragma unroll
    for (int t = 0; t < KSIZE; ++t)
        s = fmaf(g[t], src[refl224(x - KRAD + t)], s);
    outp[o] = s;
}

// ---------------------------------------------------------------------------
extern "C" void kernel_launch(void* const* d_in, const int* in_sizes, int n_in,
                              void* d_out, int out_size, void* d_ws, size_t ws_size,
                              hipStream_t stream) {
    const float* emb  = (const float*)d_in[0];
    const float* bank = (const float*)d_in[1];
    float* out = (float*)d_out;

    char* ws = (char*)d_ws;
    ull*   minpack = (ull*)(ws + WS_MINPACK);
    float* x2      = (float*)(ws + WS_X2);
    float* y2      = (float*)(ws + WS_Y2);
    float* pscore  = (float*)(ws + WS_PSCORE);
    int*   loc     = (int*)(ws + WS_LOC);
    float* bscore  = (float*)(ws + WS_BSCORE);
    int*   bmaxp   = (int*)(ws + WS_BMAXP);
    int*   bnn     = (int*)(ws + WS_BNN);
    float* dnn     = (float*)(ws + WS_DNN);
    float* amap    = (float*)(ws + WS_AMAP);
    float* tmp     = (float*)(ws + WS_TMP);

    // init packed min array to +inf
    hipMemsetAsync(minpack, 0xFF, N_EMB * sizeof(ull), stream);

    // 0: sum-of-squares
    {
        int waves = M_BANK + N_EMB;
        int blocks = (waves + 3) / 4;
        sumsq_kernel<<<blocks, 256, 0, stream>>>(emb, bank, x2, y2);
    }
    // 1: fused distance + min/argmin
    {
        dim3 grid(32, 49);
        min_dist_kernel<<<grid, 256, 0, stream>>>(emb, bank, x2, y2, minpack);
    }
    // 2: unpack
    finalize_nn_kernel<<<(N_EMB + 255) / 256, 256, 0, stream>>>(minpack, pscore, loc);
    // 3: per-batch argmax
    batch_argmax_kernel<<<BATCH, 256, 0, stream>>>(pscore, loc, bscore, bmaxp, bnn);
    // 4: d_nn
    dnn_kernel<<<M_BANK / 4, 256, 0, stream>>>(bank, y2, bnn, dnn);
    // 5: top-9 + rescore
    topk_score_kernel<<<BATCH, 256, 0, stream>>>(emb, bank, x2, y2, dnn, bscore, bmaxp, out);
    // 6: resize
    resize_kernel<<<(BATCH * OUT_WH * OUT_WH) / 256, 256, 0, stream>>>(pscore, amap);
    // 7/8: blur
    blur_v_kernel<<<(BATCH * OUT_WH * OUT_WH) / 256, 256, 0, stream>>>(amap, tmp);
    blur_h_kernel<<<(BATCH * OUT_WH * OUT_WH) / 256, 256, 0, stream>>>(tmp, out + BATCH);
}

// Round 2
// 861.398 us; speedup vs baseline: 1.4977x; 1.4977x over previous
//
#include <hip/hip_runtime.h>
#include <hip/hip_bf16.h>

// Problem constants (from setup_inputs)
#define N_EMB   6272
#define M_BANK  32768
#define D_DIM   128
#define KPACK   384      // hi|hi|lo vs hi|lo|hi packed K
#define BATCH   8
#define P_PATCH 784      // 6272 / 8
#define GRID_WH 28
#define OUT_WH  224
#define KNN     9
#define KSIZE   33
#define KRAD    16

typedef unsigned long long ull;
typedef short bf16x8 __attribute__((ext_vector_type(8)));
typedef float f32x4  __attribute__((ext_vector_type(4)));

// ---------------- workspace layout (bytes), ws ~256 MB ----------------
#define WS_MINPACK 0          // u64[6272]            -> 50176
#define WS_X2      50176      // f32[6272]            -> 75264
#define WS_Y2      75264      // f32[32768]           -> 206336
#define WS_PSCORE  206336     // f32[6272]            -> 231424
#define WS_BSCORE  231424     // f32[8]
#define WS_BMAXP   231456     // i32[8]
#define WS_BNN     231488     // i32[8]
#define WS_DNN     231552     // f32[8*32768]         -> 1280128
#define WS_TMP     1280128    // f32[8*224*224]       -> 2885760
#define WS_APK     2885888    // u16[6272*384]        -> 7702784   (16B aligned)
#define WS_BPK     7702784    // u16[32768*384]       -> 32868608  (16B aligned)

__device__ __forceinline__ ull umin64(ull a, ull b) { return a < b ? a : b; }
__device__ __forceinline__ ull umax64(ull a, ull b) { return a > b ? a : b; }

__device__ __forceinline__ void gload_lds16(const void* g, void* l) {
    __builtin_amdgcn_global_load_lds(
        (const __attribute__((address_space(1))) void*)g,
        (__attribute__((address_space(3))) void*)l, 16, 0, 0);
}

// ---------------------------------------------------------------------------
// Kernel 0 (prep): per-row bf16 hi/lo split-pack + sum-of-squares + minpack init.
// One wave per row. A rows: [hi|hi|lo]; B rows: [hi|lo|hi].
// ---------------------------------------------------------------------------
__global__ __launch_bounds__(256) void prep_kernel(
    const float* __restrict__ emb, const float* __restrict__ bank,
    unsigned short* __restrict__ Apk, unsigned short* __restrict__ Bpk,
    float* __restrict__ x2, float* __restrict__ y2, ull* __restrict__ minpack)
{
    const int tid = threadIdx.x;
    int gi = blockIdx.x * 256 + tid;
    if (gi < N_EMB) minpack[gi] = ~0ull;

    const int w    = blockIdx.x * 4 + (tid >> 6);
    const int lane = tid & 63;
    const float* src;
    unsigned short* dst;
    float* sq;
    int loOff, hi2Off;
    if (w < N_EMB) {
        src = emb + (size_t)w * D_DIM;
        dst = Apk + (size_t)w * KPACK;
        sq  = x2 + w;
        hi2Off = 128; loOff = 256;     // A: hi, hi, lo
    } else {
        int m = w - N_EMB;             // grid sized exactly -> m < M_BANK
        src = bank + (size_t)m * D_DIM;
        dst = Bpk + (size_t)m * KPACK;
        sq  = y2 + m;
        loOff = 128; hi2Off = 256;     // B: hi, lo, hi
    }
    float2 v = *(const float2*)&src[2 * lane];
    __hip_bfloat16 h0 = __float2bfloat16(v.x);
    __hip_bfloat16 h1 = __float2bfloat16(v.y);
    __hip_bfloat16 l0 = __float2bfloat16(v.x - __bfloat162float(h0));
    __hip_bfloat16 l1 = __float2bfloat16(v.y - __bfloat162float(h1));
    unsigned hb0 = *(unsigned short*)&h0, hb1 = *(unsigned short*)&h1;
    unsigned lb0 = *(unsigned short*)&l0, lb1 = *(unsigned short*)&l1;
    unsigned hpack = hb0 | (hb1 << 16);
    unsigned lpack = lb0 | (lb1 << 16);
    *(unsigned*)&dst[2 * lane]          = hpack;
    *(unsigned*)&dst[hi2Off + 2 * lane] = hpack;
    *(unsigned*)&dst[loOff + 2 * lane]  = lpack;

    float s = fmaf(v.x, v.x, v.y * v.y);
    #pragma unroll
    for (int off = 32; off > 0; off >>= 1) s += __shfl_down(s, off, 64);
    if (lane == 0) *sq = s;
}

// ---------------------------------------------------------------------------
// Kernel 1: MFMA distance + fused min/argmin.
// 128x128 tile, 16x16x32 bf16 MFMA, K=384 (hi/lo split), global_load_lds
// width-16 staging, m97 2-barrier K-loop. Epilogue: packed (d2bits<<32|m)
// min via shfl_xor within 16-lane col groups, LDS combine, atomicMin.
// ---------------------------------------------------------------------------
__global__ __launch_bounds__(256) void mfma_min_kernel(
    const unsigned short* __restrict__ Apk, const unsigned short* __restrict__ Bpk,
    const float* __restrict__ x2, const float* __restrict__ y2,
    ull* __restrict__ minpack)
{
    __shared__ __align__(16) unsigned short Asm_[128 * 32];  // 8 KB
    __shared__ __align__(16) unsigned short Bsm_[128 * 32];  // 8 KB

    const int tid  = threadIdx.x;
    const int lane = tid & 63;
    const int wave = tid >> 6;
    const int wr = wave >> 1, wc = wave & 1;
    const int n0 = blockIdx.y * 128;
    const int m0 = blockIdx.x * 128;

    const int srow = tid >> 2;   // 0..63 staging row
    const int sseg = tid & 3;    // 16B segment within 64B row-chunk

    const int qa = lane >> 4;    // k-quad
    const int ra = lane & 15;    // row-in-frag / col-in-C

    f32x4 acc[4][4];
    #pragma unroll
    for (int i = 0; i < 4; ++i)
        #pragma unroll
        for (int j = 0; j < 4; ++j)
            acc[i][j] = (f32x4){0.f, 0.f, 0.f, 0.f};

    for (int ks = 0; ks < KPACK; ks += 32) {
        __syncthreads();
        const size_t gA = (size_t)(n0 + srow) * KPACK + ks + sseg * 8;
        const size_t gB = (size_t)(m0 + srow) * KPACK + ks + sseg * 8;
        gload_lds16(Apk + gA,              &Asm_[srow * 32 + sseg * 8]);
        gload_lds16(Apk + gA + 64 * KPACK, &Asm_[(srow + 64) * 32 + sseg * 8]);
        gload_lds16(Bpk + gB,              &Bsm_[srow * 32 + sseg * 8]);
        gload_lds16(Bpk + gB + 64 * KPACK, &Bsm_[(srow + 64) * 32 + sseg * 8]);
        __syncthreads();

        bf16x8 af[4], bfr[4];
        #pragma unroll
        for (int i = 0; i < 4; ++i)
            af[i] = *(const bf16x8*)&Asm_[(wr * 64 + i * 16 + ra) * 32 + qa * 8];
        #pragma unroll
        for (int j = 0; j < 4; ++j)
            bfr[j] = *(const bf16x8*)&Bsm_[(wc * 64 + j * 16 + ra) * 32 + qa * 8];
        #pragma unroll
        for (int i = 0; i < 4; ++i)
            #pragma unroll
            for (int j = 0; j < 4; ++j)
                acc[i][j] = __builtin_amdgcn_mfma_f32_16x16x32_bf16(af[i], bfr[j], acc[i][j], 0, 0, 0);
    }

    // ---- epilogue: d2 = x2 + y2 - 2*dot, clamp, pack, reduce ----
    float y2v[4];
    #pragma unroll
    for (int j = 0; j < 4; ++j) y2v[j] = y2[m0 + wc * 64 + j * 16 + ra];

    __syncthreads();                 // all LDS frag reads done; reuse Asm_ as red
    ull* red = (ull*)Asm_;           // [128 rows][2 col-halves]
    #pragma unroll
    for (int i = 0; i < 4; ++i) {
        #pragma unroll
        for (int r = 0; r < 4; ++r) {
            const int rowl = wr * 64 + i * 16 + qa * 4 + r;
            const float xv = x2[n0 + rowl];
            ull mn = ~0ull;
            #pragma unroll
            for (int j = 0; j < 4; ++j) {
                const int m = m0 + wc * 64 + j * 16 + ra;
                float d2 = fmaf(-2.0f, acc[i][j][r], xv + y2v[j]);
                d2 = fmaxf(d2, 0.0f);
                ull p = ((ull)__float_as_uint(d2) << 32) | (unsigned)m;
                mn = umin64(mn, p);
            }
            #pragma unroll
            for (int s = 1; s < 16; s <<= 1)
                mn = umin64(mn, (ull)__shfl_xor(mn, s, 64));
            if (ra == 0) red[rowl * 2 + wc] = mn;
        }
    }
    __syncthreads();
    if (tid < 128)
        atomicMin(&minpack[n0 + tid], umin64(red[tid * 2], red[tid * 2 + 1]));
}

// ---------------------------------------------------------------------------
// Kernel 2: per-batch argmax of patch scores (fused unpack; argmax over d2
// == argmax over sqrt(d2)); writes pscore for the blur path.
// ---------------------------------------------------------------------------
__global__ __launch_bounds__(256) void batch_argmax_kernel(
    const ull* __restrict__ minpack, float* __restrict__ pscore,
    float* __restrict__ bscore, int* __restrict__ bmaxp, int* __restrict__ bnn)
{
    __shared__ ull red[256];
    int b = blockIdx.x, tid = threadIdx.x;
    ull local = 0;
    for (int p = tid; p < P_PATCH; p += 256) {
        ull mp = minpack[b * P_PATCH + p];
        unsigned d2b = (unsigned)(mp >> 32);
        pscore[b * P_PATCH + p] = sqrtf(__uint_as_float(d2b));
        ull pk = ((ull)d2b << 32) | (unsigned)(p ^ 0xFFFFFFFFu);
        local = umax64(local, pk);
    }
    red[tid] = local;
    __syncthreads();
    for (int s = 128; s > 0; s >>= 1) {
        if (tid < s) red[tid] = umax64(red[tid], red[tid + s]);
        __syncthreads();
    }
    if (tid == 0) {
        ull r = red[0];
        int p = (int)(((unsigned)(r & 0xFFFFFFFFu)) ^ 0xFFFFFFFFu);
        bscore[b] = sqrtf(__uint_as_float((unsigned)(r >> 32)));
        bmaxp[b]  = p;
        bnn[b]    = (int)(minpack[b * P_PATCH + p] & 0xFFFFFFFFu);
    }
}

// ---------------------------------------------------------------------------
// Kernel 3: d_nn = dist(nn_sample[b], memory_bank) -> (8, M)
// ---------------------------------------------------------------------------
__global__ __launch_bounds__(256) void dnn_kernel(
    const float* __restrict__ bank, const float* __restrict__ y2,
    const int* __restrict__ bnn, float* __restrict__ dnn)
{
    __shared__ float nn[BATCH][D_DIM];
    __shared__ float nny2[BATCH];
    int tid = threadIdx.x;
    for (int i = tid; i < BATCH * D_DIM; i += 256) {
        int b = i >> 7, d = i & 127;
        nn[b][d] = bank[(size_t)bnn[b] * D_DIM + d];
    }
    if (tid < BATCH) nny2[tid] = y2[bnn[tid]];
    __syncthreads();

    int w = tid >> 6, lane = tid & 63;
    int m = blockIdx.x * 4 + w;
    float2 v = *(const float2*)&bank[(size_t)m * D_DIM + 2 * lane];
    float part[BATCH];
    #pragma unroll
    for (int b = 0; b < BATCH; ++b)
        part[b] = fmaf(v.x, nn[b][2 * lane], v.y * nn[b][2 * lane + 1]);
    #pragma unroll
    for (int b = 0; b < BATCH; ++b) {
        float s = part[b];
        #pragma unroll
        for (int off = 32; off > 0; off >>= 1) s += __shfl_down(s, off, 64);
        if (lane == 0) {
            float d2 = nny2[b] + y2[m] - 2.0f * s;
            dnn[b * M_BANK + m] = sqrtf(fmaxf(d2, 0.0f));
        }
    }
}

// ---------------------------------------------------------------------------
// Kernel 4: per-batch top-9 smallest d_nn (lowest-index tie-break) + rescore
// ---------------------------------------------------------------------------
__global__ __launch_bounds__(256) void topk_score_kernel(
    const float* __restrict__ emb, const float* __restrict__ bank,
    const float* __restrict__ x2, const float* __restrict__ y2,
    const float* __restrict__ dnn, const float* __restrict__ bscore,
    const int* __restrict__ bmaxp, float* __restrict__ out)
{
    __shared__ ull red[256];
    __shared__ int chosen[KNN];
    __shared__ float dists[KNN];
    int b = blockIdx.x, tid = threadIdx.x;

    for (int k = 0; k < KNN; ++k) {
        ull local = ~0ull;
        for (int i = tid; i < M_BANK; i += 256) {
            bool skip = false;
            for (int j = 0; j < k; ++j) skip |= (chosen[j] == i);
            if (!skip) {
                float d = dnn[b * M_BANK + i];
                ull pk = ((ull)__float_as_uint(d) << 32) | (unsigned)i;
                local = umin64(local, pk);
            }
        }
        red[tid] = local;
        __syncthreads();
        for (int s = 128; s > 0; s >>= 1) {
            if (tid < s) red[tid] = umin64(red[tid], red[tid + s]);
            __syncthreads();
        }
        if (tid == 0) chosen[k] = (int)(red[0] & 0xFFFFFFFFu);
        __syncthreads();
    }

    int e = b * P_PATCH + bmaxp[b];
    if (tid < KNN) {
        const float* mf = emb + (size_t)e * D_DIM;
        const float* ms = bank + (size_t)chosen[tid] * D_DIM;
        float dot = 0.0f;
        for (int d = 0; d < D_DIM; ++d) dot = fmaf(mf[d], ms[d], dot);
        float d2 = x2[e] - 2.0f * dot + y2[chosen[tid]];
        dists[tid] = sqrtf(fmaxf(d2, 0.0f));
    }
    __syncthreads();
    if (tid == 0) {
        float mx = dists[0];
        for (int k = 1; k < KNN; ++k) mx = fmaxf(mx, dists[k]);
        float s = 0.0f;
        for (int k = 0; k < KNN; ++k) s += expf(dists[k] - mx);
        float w = 1.0f - expf(dists[0] - mx) / s;
        out[b] = w * bscore[b];
    }
}

// ---------------------------------------------------------------------------
// Kernels 5/6: Gaussian blur; vertical pass samples the bilinear resize
// on the fly from pscore (resize kernel fused away).
// ---------------------------------------------------------------------------
__device__ __forceinline__ int refl224(int i) {
    if (i < 0) i = -i;
    if (i >= OUT_WH) i = 2 * (OUT_WH - 1) - i;
    return i;
}

__device__ __forceinline__ void make_gauss(float* g, int tid) {
    if (tid < KSIZE) {
        float x = (tid - KRAD) * 0.25f;   // / SIGMA=4
        g[tid] = __expf(-0.5f * x * x);
    }
    __syncthreads();
    if (tid == 0) {
        float s = 0.0f;
        for (int i = 0; i < KSIZE; ++i) s += g[i];
        float inv = 1.0f / s;
        for (int i = 0; i < KSIZE; ++i) g[i] *= inv;
    }
    __syncthreads();
}

__global__ __launch_bounds__(256) void blur_v_kernel(
    const float* __restrict__ pscore, float* __restrict__ outp)
{
    __shared__ float g[KSIZE];
    int tid = threadIdx.x;
    make_gauss(g, tid);
    int o = blockIdx.x * 256 + tid;
    int b = o / (OUT_WH * OUT_WH);
    int y = (o / OUT_WH) % OUT_WH;
    int x = o % OUT_WH;
    const float* ps = pscore + b * P_PATCH;
    float cx = (2 * x - 7) * 0.0625f;
    int ix = (int)floorf(cx); float fx = cx - ix;
    int x0 = min(max(ix, 0), GRID_WH - 1), x1 = min(max(ix + 1, 0), GRID_WH - 1);
    float s = 0.0f;
    #pragma unroll
    for (int t = 0; t < KSIZE; ++t) {
        int yy = refl224(y - KRAD + t);
        float cy = (2 * yy - 7) * 0.0625f;
        int iy = (int)floorf(cy); float fy = cy - iy;
        int y0 = min(max(iy, 0), GRID_WH - 1), y1 = min(max(iy + 1, 0), GRID_WH - 1);
        float top = ps[y0 * GRID_WH + x0] * (1.0f - fx) + ps[y0 * GRID_WH + x1] * fx;
        float bot = ps[y1 * GRID_WH + x0] * (1.0f - fx) + ps[y1 * GRID_WH + x1] * fx;
        s = fmaf(g[t], (1.0f - fy) * top + fy * bot, s);
    }
    outp[o] = s;
}

__global__ __launch_bounds__(256) void blur_h_kernel(
    const float* __restrict__ in, float* __restrict__ outp)
{
    __shared__ float g[KSIZE];
    int tid = threadIdx.x;
    make_gauss(g, tid);
    int o = blockIdx.x * 256 + tid;
    int b = o / (OUT_WH * OUT_WH);
    int y = (o / OUT_WH) % OUT_WH;
    int x = o % OUT_WH;
    const float* src = in + (size_t)b * OUT_WH * OUT_WH + (size_t)y * OUT_WH;
    float s = 0.0f;
    #pragma unroll
    for (int t = 0; t < KSIZE; ++t)
        s = fmaf(g[t], src[refl224(x - KRAD + t)], s);
    outp[o] = s;
}

// ---------------------------------------------------------------------------
extern "C" void kernel_launch(void* const* d_in, const int* in_sizes, int n_in,
                              void* d_out, int out_size, void* d_ws, size_t ws_size,
                              hipStream_t stream) {
    const float* emb  = (const float*)d_in[0];
    const float* bank = (const float*)d_in[1];
    float* out = (float*)d_out;

    char* ws = (char*)d_ws;
    ull*   minpack = (ull*)(ws + WS_MINPACK);
    float* x2      = (float*)(ws + WS_X2);
    float* y2      = (float*)(ws + WS_Y2);
    float* pscore  = (float*)(ws + WS_PSCORE);
    float* bscore  = (float*)(ws + WS_BSCORE);
    int*   bmaxp   = (int*)(ws + WS_BMAXP);
    int*   bnn     = (int*)(ws + WS_BNN);
    float* dnn     = (float*)(ws + WS_DNN);
    float* tmp     = (float*)(ws + WS_TMP);
    unsigned short* Apk = (unsigned short*)(ws + WS_APK);
    unsigned short* Bpk = (unsigned short*)(ws + WS_BPK);

    // 0: split-pack + sumsq + minpack init (one wave per row)
    prep_kernel<<<(N_EMB + M_BANK) / 4, 256, 0, stream>>>(emb, bank, Apk, Bpk, x2, y2, minpack);
    // 1: MFMA distance + fused min/argmin
    {
        dim3 grid(M_BANK / 128, N_EMB / 128);   // 256 x 49
        mfma_min_kernel<<<grid, 256, 0, stream>>>(Apk, Bpk, x2, y2, minpack);
    }
    // 2: per-batch argmax (+ pscore unpack)
    batch_argmax_kernel<<<BATCH, 256, 0, stream>>>(minpack, pscore, bscore, bmaxp, bnn);
    // 3: d_nn
    dnn_kernel<<<M_BANK / 4, 256, 0, stream>>>(bank, y2, bnn, dnn);
    // 4: top-9 + rescore -> out[0..7]
    topk_score_kernel<<<BATCH, 256, 0, stream>>>(emb, bank, x2, y2, dnn, bscore, bmaxp, out);
    // 5: fused resize + vertical blur
    blur_v_kernel<<<(BATCH * OUT_WH * OUT_WH) / 256, 256, 0, stream>>>(pscore, tmp);
    // 6: horizontal blur -> out[8..]
    blur_h_kernel<<<(BATCH * OUT_WH * OUT_WH) / 256, 256, 0, stream>>>(tmp, out + BATCH);
}

// Round 3
// 421.767 us; speedup vs baseline: 3.0588x; 2.0424x over previous
//
#include <hip/hip_runtime.h>
#include <hip/hip_bf16.h>

// Problem constants (from setup_inputs)
#define N_EMB   6272
#define M_BANK  32768
#define D_DIM   128
#define KPACK   384      // hi|hi|lo vs hi|lo|hi packed K
#define BATCH   8
#define P_PATCH 784      // 6272 / 8
#define GRID_WH 28
#define OUT_WH  224
#define KNN     9
#define KSIZE   33
#define KRAD    16

typedef unsigned long long ull;
typedef short bf16x8 __attribute__((ext_vector_type(8)));
typedef float f32x4  __attribute__((ext_vector_type(4)));

// ---------------- workspace layout (bytes), ws ~256 MB ----------------
#define WS_MINPACK 0          // u64[6272]            -> 50176
#define WS_X2      50176      // f32[6272]            -> 75264
#define WS_Y2      75264      // f32[32768]           -> 206336
#define WS_PSCORE  206336     // f32[6272]            -> 231424
#define WS_BSCORE  231424     // f32[8]
#define WS_BMAXP   231456     // i32[8]
#define WS_BNN     231488     // i32[8]
#define WS_DNN     231552     // f32[8*32768]         -> 1280128
#define WS_TMP     1280128    // f32[8*224*224]       -> 2885760
#define WS_APK     2885888    // u16[6272*384]        -> 7702784   (16B aligned)
#define WS_BPK     7702784    // u16[32768*384]       -> 32868608  (16B aligned)
#define WS_CAND    32868608   // u64[8*32*9]          -> 32887040

__device__ __forceinline__ ull umin64(ull a, ull b) { return a < b ? a : b; }
__device__ __forceinline__ ull umax64(ull a, ull b) { return a > b ? a : b; }

__device__ __forceinline__ void gload_lds16(const void* g, void* l) {
    __builtin_amdgcn_global_load_lds(
        (const __attribute__((address_space(1))) void*)g,
        (__attribute__((address_space(3))) void*)l, 16, 0, 0);
}

// ---------------------------------------------------------------------------
// Kernel 0 (prep): per-row bf16 hi/lo split-pack + sum-of-squares + minpack init.
// One wave per row. A rows: [hi|hi|lo]; B rows: [hi|lo|hi].
// ---------------------------------------------------------------------------
__global__ __launch_bounds__(256) void prep_kernel(
    const float* __restrict__ emb, const float* __restrict__ bank,
    unsigned short* __restrict__ Apk, unsigned short* __restrict__ Bpk,
    float* __restrict__ x2, float* __restrict__ y2, ull* __restrict__ minpack)
{
    const int tid = threadIdx.x;
    int gi = blockIdx.x * 256 + tid;
    if (gi < N_EMB) minpack[gi] = ~0ull;

    const int w    = blockIdx.x * 4 + (tid >> 6);
    const int lane = tid & 63;
    const float* src;
    unsigned short* dst;
    float* sq;
    int loOff, hi2Off;
    if (w < N_EMB) {
        src = emb + (size_t)w * D_DIM;
        dst = Apk + (size_t)w * KPACK;
        sq  = x2 + w;
        hi2Off = 128; loOff = 256;     // A: hi, hi, lo
    } else {
        int m = w - N_EMB;             // grid sized exactly -> m < M_BANK
        src = bank + (size_t)m * D_DIM;
        dst = Bpk + (size_t)m * KPACK;
        sq  = y2 + m;
        loOff = 128; hi2Off = 256;     // B: hi, lo, hi
    }
    float2 v = *(const float2*)&src[2 * lane];
    __hip_bfloat16 h0 = __float2bfloat16(v.x);
    __hip_bfloat16 h1 = __float2bfloat16(v.y);
    __hip_bfloat16 l0 = __float2bfloat16(v.x - __bfloat162float(h0));
    __hip_bfloat16 l1 = __float2bfloat16(v.y - __bfloat162float(h1));
    unsigned hb0 = *(unsigned short*)&h0, hb1 = *(unsigned short*)&h1;
    unsigned lb0 = *(unsigned short*)&l0, lb1 = *(unsigned short*)&l1;
    unsigned hpack = hb0 | (hb1 << 16);
    unsigned lpack = lb0 | (lb1 << 16);
    *(unsigned*)&dst[2 * lane]          = hpack;
    *(unsigned*)&dst[hi2Off + 2 * lane] = hpack;
    *(unsigned*)&dst[loOff + 2 * lane]  = lpack;

    float s = fmaf(v.x, v.x, v.y * v.y);
    #pragma unroll
    for (int off = 32; off > 0; off >>= 1) s += __shfl_down(s, off, 64);
    if (lane == 0) *sq = s;
}

// ---------------------------------------------------------------------------
// Kernel 1: MFMA distance + fused min/argmin.
// 128x128 tile, 16x16x32 bf16 MFMA, K=384 (hi/lo split), global_load_lds
// width-16 staging, m97 2-barrier K-loop. Epilogue: packed (d2bits<<32|m)
// min via shfl_xor within 16-lane col groups, LDS combine, atomicMin.
// ---------------------------------------------------------------------------
__global__ __launch_bounds__(256) void mfma_min_kernel(
    const unsigned short* __restrict__ Apk, const unsigned short* __restrict__ Bpk,
    const float* __restrict__ x2, const float* __restrict__ y2,
    ull* __restrict__ minpack)
{
    __shared__ __align__(16) unsigned short Asm_[128 * 32];  // 8 KB
    __shared__ __align__(16) unsigned short Bsm_[128 * 32];  // 8 KB

    const int tid  = threadIdx.x;
    const int lane = tid & 63;
    const int wave = tid >> 6;
    const int wr = wave >> 1, wc = wave & 1;
    const int n0 = blockIdx.y * 128;
    const int m0 = blockIdx.x * 128;

    const int srow = tid >> 2;   // 0..63 staging row
    const int sseg = tid & 3;    // 16B segment within 64B row-chunk

    const int qa = lane >> 4;    // k-quad
    const int ra = lane & 15;    // row-in-frag / col-in-C

    f32x4 acc[4][4];
    #pragma unroll
    for (int i = 0; i < 4; ++i)
        #pragma unroll
        for (int j = 0; j < 4; ++j)
            acc[i][j] = (f32x4){0.f, 0.f, 0.f, 0.f};

    for (int ks = 0; ks < KPACK; ks += 32) {
        __syncthreads();
        const size_t gA = (size_t)(n0 + srow) * KPACK + ks + sseg * 8;
        const size_t gB = (size_t)(m0 + srow) * KPACK + ks + sseg * 8;
        gload_lds16(Apk + gA,              &Asm_[srow * 32 + sseg * 8]);
        gload_lds16(Apk + gA + 64 * KPACK, &Asm_[(srow + 64) * 32 + sseg * 8]);
        gload_lds16(Bpk + gB,              &Bsm_[srow * 32 + sseg * 8]);
        gload_lds16(Bpk + gB + 64 * KPACK, &Bsm_[(srow + 64) * 32 + sseg * 8]);
        __syncthreads();

        bf16x8 af[4], bfr[4];
        #pragma unroll
        for (int i = 0; i < 4; ++i)
            af[i] = *(const bf16x8*)&Asm_[(wr * 64 + i * 16 + ra) * 32 + qa * 8];
        #pragma unroll
        for (int j = 0; j < 4; ++j)
            bfr[j] = *(const bf16x8*)&Bsm_[(wc * 64 + j * 16 + ra) * 32 + qa * 8];
        #pragma unroll
        for (int i = 0; i < 4; ++i)
            #pragma unroll
            for (int j = 0; j < 4; ++j)
                acc[i][j] = __builtin_amdgcn_mfma_f32_16x16x32_bf16(af[i], bfr[j], acc[i][j], 0, 0, 0);
    }

    // ---- epilogue: d2 = x2 + y2 - 2*dot, clamp, pack, reduce ----
    float y2v[4];
    #pragma unroll
    for (int j = 0; j < 4; ++j) y2v[j] = y2[m0 + wc * 64 + j * 16 + ra];

    __syncthreads();                 // all LDS frag reads done; reuse Asm_ as red
    ull* red = (ull*)Asm_;           // [128 rows][2 col-halves]
    #pragma unroll
    for (int i = 0; i < 4; ++i) {
        #pragma unroll
        for (int r = 0; r < 4; ++r) {
            const int rowl = wr * 64 + i * 16 + qa * 4 + r;
            const float xv = x2[n0 + rowl];
            ull mn = ~0ull;
            #pragma unroll
            for (int j = 0; j < 4; ++j) {
                const int m = m0 + wc * 64 + j * 16 + ra;
                float d2 = fmaf(-2.0f, acc[i][j][r], xv + y2v[j]);
                d2 = fmaxf(d2, 0.0f);
                ull p = ((ull)__float_as_uint(d2) << 32) | (unsigned)m;
                mn = umin64(mn, p);
            }
            #pragma unroll
            for (int s = 1; s < 16; s <<= 1)
                mn = umin64(mn, (ull)__shfl_xor(mn, s, 64));
            if (ra == 0) red[rowl * 2 + wc] = mn;
        }
    }
    __syncthreads();
    if (tid < 128)
        atomicMin(&minpack[n0 + tid], umin64(red[tid * 2], red[tid * 2 + 1]));
}

// ---------------------------------------------------------------------------
// Kernel 2: per-batch argmax of patch scores (fused unpack; argmax over d2
// == argmax over sqrt(d2)); writes pscore for the blur path.
// ---------------------------------------------------------------------------
__global__ __launch_bounds__(256) void batch_argmax_kernel(
    const ull* __restrict__ minpack, float* __restrict__ pscore,
    float* __restrict__ bscore, int* __restrict__ bmaxp, int* __restrict__ bnn)
{
    __shared__ ull red[256];
    int b = blockIdx.x, tid = threadIdx.x;
    ull local = 0;
    for (int p = tid; p < P_PATCH; p += 256) {
        ull mp = minpack[b * P_PATCH + p];
        unsigned d2b = (unsigned)(mp >> 32);
        pscore[b * P_PATCH + p] = sqrtf(__uint_as_float(d2b));
        ull pk = ((ull)d2b << 32) | (unsigned)(p ^ 0xFFFFFFFFu);
        local = umax64(local, pk);
    }
    red[tid] = local;
    __syncthreads();
    for (int s = 128; s > 0; s >>= 1) {
        if (tid < s) red[tid] = umax64(red[tid], red[tid + s]);
        __syncthreads();
    }
    if (tid == 0) {
        ull r = red[0];
        int p = (int)(((unsigned)(r & 0xFFFFFFFFu)) ^ 0xFFFFFFFFu);
        bscore[b] = sqrtf(__uint_as_float((unsigned)(r >> 32)));
        bmaxp[b]  = p;
        bnn[b]    = (int)(minpack[b * P_PATCH + p] & 0xFFFFFFFFu);
    }
}

// ---------------------------------------------------------------------------
// Kernel 3: d_nn = dist(nn_sample[b], memory_bank) -> (8, M)
// ---------------------------------------------------------------------------
__global__ __launch_bounds__(256) void dnn_kernel(
    const float* __restrict__ bank, const float* __restrict__ y2,
    const int* __restrict__ bnn, float* __restrict__ dnn)
{
    __shared__ float nn[BATCH][D_DIM];
    __shared__ float nny2[BATCH];
    int tid = threadIdx.x;
    for (int i = tid; i < BATCH * D_DIM; i += 256) {
        int b = i >> 7, d = i & 127;
        nn[b][d] = bank[(size_t)bnn[b] * D_DIM + d];
    }
    if (tid < BATCH) nny2[tid] = y2[bnn[tid]];
    __syncthreads();

    int w = tid >> 6, lane = tid & 63;
    int m = blockIdx.x * 4 + w;
    float2 v = *(const float2*)&bank[(size_t)m * D_DIM + 2 * lane];
    float part[BATCH];
    #pragma unroll
    for (int b = 0; b < BATCH; ++b)
        part[b] = fmaf(v.x, nn[b][2 * lane], v.y * nn[b][2 * lane + 1]);
    #pragma unroll
    for (int b = 0; b < BATCH; ++b) {
        float s = part[b];
        #pragma unroll
        for (int off = 32; off > 0; off >>= 1) s += __shfl_down(s, off, 64);
        if (lane == 0) {
            float d2 = nny2[b] + y2[m] - 2.0f * s;
            dnn[b * M_BANK + m] = sqrtf(fmaxf(d2, 0.0f));
        }
    }
}

// ---------------------------------------------------------------------------
// Kernel 4a: per-(batch, 1024-chunk) local top-9 of d_nn.
// Packed values live in LDS; 9 rounds of tree-min with removal-by-equality.
// Grid: (32 chunks, 8 batches). One global pass over dnn total.
// ---------------------------------------------------------------------------
__global__ __launch_bounds__(256) void topk_part_kernel(
    const float* __restrict__ dnn, ull* __restrict__ cand)
{
    __shared__ ull vals[1024];
    __shared__ ull red[256];
    const int tid = threadIdx.x;
    const int b = blockIdx.y, ch = blockIdx.x;
    const int base = ch * 1024;

    #pragma unroll
    for (int j = 0; j < 4; ++j) {
        int i = base + tid + j * 256;
        vals[tid + j * 256] = ((ull)__float_as_uint(dnn[b * M_BANK + i]) << 32) | (unsigned)i;
    }
    __syncthreads();

    for (int k = 0; k < KNN; ++k) {
        ull local = vals[tid];
        #pragma unroll
        for (int j = 1; j < 4; ++j) local = umin64(local, vals[tid + j * 256]);
        red[tid] = local;
        __syncthreads();
        for (int s = 128; s > 0; s >>= 1) {
            if (tid < s) red[tid] = umin64(red[tid], red[tid + s]);
            __syncthreads();
        }
        ull win = red[0];
        if (tid == 0) cand[(b * 32 + ch) * KNN + k] = win;
        // remove winner (packed value is unique: index embedded)
        #pragma unroll
        for (int j = 0; j < 4; ++j)
            if (vals[tid + j * 256] == win) vals[tid + j * 256] = ~0ull;
        __syncthreads();
    }
}

// ---------------------------------------------------------------------------
// Kernel 4b: per-batch final top-9 from 288 candidates + rescore
// (dists from max_feat to the support set, softmax, pred_score).
// ---------------------------------------------------------------------------
__global__ __launch_bounds__(256) void topk_final_kernel(
    const ull* __restrict__ cand,
    const float* __restrict__ emb, const float* __restrict__ bank,
    const float* __restrict__ x2, const float* __restrict__ y2,
    const float* __restrict__ bscore, const int* __restrict__ bmaxp,
    float* __restrict__ out)
{
    __shared__ ull vals[512];
    __shared__ ull red[256];
    __shared__ int chosen[KNN];
    __shared__ float dists[KNN];
    const int tid = threadIdx.x;
    const int b = blockIdx.x;

    vals[tid]       = (tid < 32 * KNN) ? cand[b * 32 * KNN + tid] : ~0ull;
    vals[tid + 256] = (tid + 256 < 32 * KNN) ? cand[b * 32 * KNN + tid + 256] : ~0ull;
    __syncthreads();

    for (int k = 0; k < KNN; ++k) {
        red[tid] = umin64(vals[tid], vals[tid + 256]);
        __syncthreads();
        for (int s = 128; s > 0; s >>= 1) {
            if (tid < s) red[tid] = umin64(red[tid], red[tid + s]);
            __syncthreads();
        }
        ull win = red[0];
        if (tid == 0) chosen[k] = (int)(win & 0xFFFFFFFFu);
        if (vals[tid] == win) vals[tid] = ~0ull;
        if (vals[tid + 256] == win) vals[tid + 256] = ~0ull;
        __syncthreads();
    }

    const int e = b * P_PATCH + bmaxp[b];
    if (tid < KNN) {
        const float* mf = emb + (size_t)e * D_DIM;
        const float* ms = bank + (size_t)chosen[tid] * D_DIM;
        float dot = 0.0f;
        for (int d = 0; d < D_DIM; ++d) dot = fmaf(mf[d], ms[d], dot);
        float d2 = x2[e] - 2.0f * dot + y2[chosen[tid]];
        dists[tid] = sqrtf(fmaxf(d2, 0.0f));
    }
    __syncthreads();
    if (tid == 0) {
        float mx = dists[0];
        for (int k = 1; k < KNN; ++k) mx = fmaxf(mx, dists[k]);
        float s = 0.0f;
        for (int k = 0; k < KNN; ++k) s += expf(dists[k] - mx);
        float w = 1.0f - expf(dists[0] - mx) / s;
        out[b] = w * bscore[b];
    }
}

// ---------------------------------------------------------------------------
// Kernels 5/6: Gaussian blur; vertical pass samples the bilinear resize
// on the fly from pscore (resize kernel fused away).
// ---------------------------------------------------------------------------
__device__ __forceinline__ int refl224(int i) {
    if (i < 0) i = -i;
    if (i >= OUT_WH) i = 2 * (OUT_WH - 1) - i;
    return i;
}

__device__ __forceinline__ void make_gauss(float* g, int tid) {
    if (tid < KSIZE) {
        float x = (tid - KRAD) * 0.25f;   // / SIGMA=4
        g[tid] = __expf(-0.5f * x * x);
    }
    __syncthreads();
    if (tid == 0) {
        float s = 0.0f;
        for (int i = 0; i < KSIZE; ++i) s += g[i];
        float inv = 1.0f / s;
        for (int i = 0; i < KSIZE; ++i) g[i] *= inv;
    }
    __syncthreads();
}

__global__ __launch_bounds__(256) void blur_v_kernel(
    const float* __restrict__ pscore, float* __restrict__ outp)
{
    __shared__ float g[KSIZE];
    int tid = threadIdx.x;
    make_gauss(g, tid);
    int o = blockIdx.x * 256 + tid;
    int b = o / (OUT_WH * OUT_WH);
    int y = (o / OUT_WH) % OUT_WH;
    int x = o % OUT_WH;
    const float* ps = pscore + b * P_PATCH;
    float cx = (2 * x - 7) * 0.0625f;
    int ix = (int)floorf(cx); float fx = cx - ix;
    int x0 = min(max(ix, 0), GRID_WH - 1), x1 = min(max(ix + 1, 0), GRID_WH - 1);
    float s = 0.0f;
    #pragma unroll
    for (int t = 0; t < KSIZE; ++t) {
        int yy = refl224(y - KRAD + t);
        float cy = (2 * yy - 7) * 0.0625f;
        int iy = (int)floorf(cy); float fy = cy - iy;
        int y0 = min(max(iy, 0), GRID_WH - 1), y1 = min(max(iy + 1, 0), GRID_WH - 1);
        float top = ps[y0 * GRID_WH + x0] * (1.0f - fx) + ps[y0 * GRID_WH + x1] * fx;
        float bot = ps[y1 * GRID_WH + x0] * (1.0f - fx) + ps[y1 * GRID_WH + x1] * fx;
        s = fmaf(g[t], (1.0f - fy) * top + fy * bot, s);
    }
    outp[o] = s;
}

__global__ __launch_bounds__(256) void blur_h_kernel(
    const float* __restrict__ in, float* __restrict__ outp)
{
    __shared__ float g[KSIZE];
    int tid = threadIdx.x;
    make_gauss(g, tid);
    int o = blockIdx.x * 256 + tid;
    int b = o / (OUT_WH * OUT_WH);
    int y = (o / OUT_WH) % OUT_WH;
    int x = o % OUT_WH;
    const float* src = in + (size_t)b * OUT_WH * OUT_WH + (size_t)y * OUT_WH;
    float s = 0.0f;
    #pragma unroll
    for (int t = 0; t < KSIZE; ++t)
        s = fmaf(g[t], src[refl224(x - KRAD + t)], s);
    outp[o] = s;
}

// ---------------------------------------------------------------------------
extern "C" void kernel_launch(void* const* d_in, const int* in_sizes, int n_in,
                              void* d_out, int out_size, void* d_ws, size_t ws_size,
                              hipStream_t stream) {
    const float* emb  = (const float*)d_in[0];
    const float* bank = (const float*)d_in[1];
    float* out = (float*)d_out;

    char* ws = (char*)d_ws;
    ull*   minpack = (ull*)(ws + WS_MINPACK);
    float* x2      = (float*)(ws + WS_X2);
    float* y2      = (float*)(ws + WS_Y2);
    float* pscore  = (float*)(ws + WS_PSCORE);
    float* bscore  = (float*)(ws + WS_BSCORE);
    int*   bmaxp   = (int*)(ws + WS_BMAXP);
    int*   bnn     = (int*)(ws + WS_BNN);
    float* dnn     = (float*)(ws + WS_DNN);
    float* tmp     = (float*)(ws + WS_TMP);
    unsigned short* Apk = (unsigned short*)(ws + WS_APK);
    unsigned short* Bpk = (unsigned short*)(ws + WS_BPK);
    ull*   cand    = (ull*)(ws + WS_CAND);

    // 0: split-pack + sumsq + minpack init (one wave per row)
    prep_kernel<<<(N_EMB + M_BANK) / 4, 256, 0, stream>>>(emb, bank, Apk, Bpk, x2, y2, minpack);
    // 1: MFMA distance + fused min/argmin
    {
        dim3 grid(M_BANK / 128, N_EMB / 128);   // 256 x 49
        mfma_min_kernel<<<grid, 256, 0, stream>>>(Apk, Bpk, x2, y2, minpack);
    }
    // 2: per-batch argmax (+ pscore unpack)
    batch_argmax_kernel<<<BATCH, 256, 0, stream>>>(minpack, pscore, bscore, bmaxp, bnn);
    // 3: d_nn
    dnn_kernel<<<M_BANK / 4, 256, 0, stream>>>(bank, y2, bnn, dnn);
    // 4a: per-chunk top-9 candidates
    {
        dim3 grid(32, BATCH);
        topk_part_kernel<<<grid, 256, 0, stream>>>(dnn, cand);
    }
    // 4b: final top-9 + rescore -> out[0..7]
    topk_final_kernel<<<BATCH, 256, 0, stream>>>(cand, emb, bank, x2, y2, bscore, bmaxp, out);
    // 5: fused resize + vertical blur
    blur_v_kernel<<<(BATCH * OUT_WH * OUT_WH) / 256, 256, 0, stream>>>(pscore, tmp);
    // 6: horizontal blur -> out[8..]
    blur_h_kernel<<<(BATCH * OUT_WH * OUT_WH) / 256, 256, 0, stream>>>(tmp, out + BATCH);
}